// Round 17
// baseline (37540.387 us; speedup 1.0000x reference)
//
#include <hip/hip_runtime.h>
#include <math.h>
#include <string.h>

#define TOUT 500
#define AOFF 1296000
#define GOFF 1280000
#define TF_BITS_XOR 1

typedef float f32x4 __attribute__((ext_vector_type(4)));
typedef short bf16x8 __attribute__((ext_vector_type(8)));
typedef unsigned short ushort4_t __attribute__((ext_vector_type(4)));
typedef unsigned u32x4 __attribute__((ext_vector_type(4)));

struct Params {
  const float *memory, *dec_in, *pw1, *pw2, *awih, *awhh, *abih, *abhh;
  const float *qw, *mw, *vw, *lcw, *ldw, *dwih, *dwhh, *dbih, *dbhh;
  const float *pjw, *pjb, *gw, *gb;
  const int* mlen;
  float* out;
  // mutable cross-WG state (bf16), memset each launch
  unsigned short *ahb0, *ahb1, *dhb0, *dhb1, *ctxb0, *ctxb1;
  unsigned *slots;  // [256] stride 32 words (128B lines)
  unsigned *flags;  // [8] stride 32
  // static precomputed
  float *x1, *w1t, *w2t, *mwt, *ldwt, *ba, *bd;
  unsigned short *pre_bf, *pm_bf, *mem_t, *qw_bf, *wpa, *wpd;
  unsigned *mma, *mmd, *mm1, *mm2;
};

// ---------------- threefry2x32 (matches jax partitionable path) ----------------
__host__ __device__ inline void tf_block(unsigned k0, unsigned k1, unsigned x0, unsigned x1,
                                         unsigned& o0, unsigned& o1) {
  unsigned ks2 = k0 ^ k1 ^ 0x1BD11BDAu;
  x0 += k0; x1 += k1;
#define TFR(r) { x0 += x1; x1 = (x1 << r) | (x1 >> (32 - r)); x1 ^= x0; }
  TFR(13) TFR(15) TFR(26) TFR(6)
  x0 += k1;  x1 += ks2 + 1u;
  TFR(17) TFR(29) TFR(16) TFR(24)
  x0 += ks2; x1 += k0 + 2u;
  TFR(13) TFR(15) TFR(26) TFR(6)
  x0 += k0;  x1 += k1 + 3u;
  TFR(17) TFR(29) TFR(16) TFR(24)
  x0 += k1;  x1 += ks2 + 4u;
  TFR(13) TFR(15) TFR(26) TFR(6)
  x0 += ks2; x1 += k0 + 5u;
#undef TFR
  o0 = x0; o1 = x1;
}

__device__ inline float sigf(float x) { return 1.f / (1.f + __expf(-x)); }
__device__ inline float tanh_fast(float x) {
  float ax = fabsf(x);
  float t = __expf(-2.f * ax);
  float r = (1.f - t) / (1.f + t);
  return copysignf(r, x);
}
__device__ inline unsigned short f2bf(float f) {
  unsigned u = __float_as_uint(f);
  unsigned r = (u + 0x7FFFu + ((u >> 16) & 1u)) >> 16;
  return (unsigned short)r;
}
__device__ inline float bf2f(unsigned short u) {
  return __uint_as_float((unsigned)u << 16);
}

// Barrier flags: sc0sc1 (never cached). State STORES: sc0sc1 (write-through to
// the memory side, visible to all XCDs). State READS: NORMAL cached loads —
// correctness restored by one fence(acquire,"agent") = buffer_inv per barrier,
// which is cheap now that weights/pjw are VGPR-resident (R9's mistake inverted).
__device__ inline unsigned ld_coh32(const unsigned* ptr) {
  return __hip_atomic_load(ptr, __ATOMIC_RELAXED, __HIP_MEMORY_SCOPE_SYSTEM);
}
__device__ inline void st_coh32(unsigned* ptr, unsigned v) {
  __hip_atomic_store(ptr, v, __ATOMIC_RELAXED, __HIP_MEMORY_SCOPE_SYSTEM);
}

// 16B load issued without implicit waitcnt pairing — batch-issue, drain once.
__device__ __forceinline__ u32x4 ld16(const void* ptr) {
  u32x4 r;
  asm volatile("global_load_dwordx4 %0, %1, off" : "=v"(r) : "v"(ptr));
  return r;
}

#define LD4(p) (*(const float4*)(p))

// ---------------- mask generation (bit-packed) ----------------
__global__ void maskgen_kernel(Params p, unsigned k1a, unsigned k1b, unsigned k2a, unsigned k2b,
                               unsigned k3a, unsigned k3b, unsigned k4a, unsigned k4b) {
  int t = blockIdx.x * 256 + threadIdx.x;
  unsigned ka, kb; unsigned* dst; float pp;
  if (t < 512000)       { ka = k3a; kb = k3b; dst = p.mma; pp = 0.9f; }
  else if (t < 1024000) { t -= 512000;  ka = k4a; kb = k4b; dst = p.mmd; pp = 0.9f; }
  else if (t < 1152256) { t -= 1024000; ka = k1a; kb = k1b; dst = p.mm1; pp = 0.5f; }
  else if (t < 1280512) { t -= 1152256; ka = k2a; kb = k2b; dst = p.mm2; pp = 0.5f; }
  else return;
  unsigned word = 0u;
  for (int i = 0; i < 32; ++i) {
    unsigned o0, o1;
    tf_block(ka, kb, 0u, (unsigned)t * 32u + (unsigned)i, o0, o1);
#if TF_BITS_XOR
    unsigned bits = o0 ^ o1;
#else
    unsigned bits = o0;
#endif
    unsigned fb = (bits >> 9) | 0x3f800000u;
    float u = __uint_as_float(fb) - 1.0f;
    if (u < pp) word |= (1u << i);
  }
  dst[t] = word;
}

// ---------------- misc static prep ----------------
__global__ void prep_misc(Params p) {
  int i = blockIdx.x * 256 + threadIdx.x;
  if (i < 20480) { int k = i >> 8, u = i & 255; p.w1t[i] = p.pw1[u * 80 + k]; return; }
  i -= 20480;
  if (i < 65536) { int k = i >> 8, u = i & 255; p.w2t[i] = p.pw2[u * 256 + k]; return; }
  i -= 65536;
  if (i < 65536) { int k = i >> 7, a = i & 127; p.mwt[i] = p.mw[a * 512 + k]; return; }
  i -= 65536;
  if (i < 131072) { p.qw_bf[i] = f2bf(p.qw[i]); return; }
  i -= 131072;
  if (i < 4096) { int f = i >> 7, a = i & 127; p.ldwt[i] = p.ldw[a * 32 + f]; return; }
  i -= 4096;
  if (i < 4096) { int col = (i & 3) * 1024 + (i >> 2); p.ba[i] = p.abih[col] + p.abhh[col]; return; }
  i -= 4096;
  if (i < 4096) { int col = (i & 3) * 1024 + (i >> 2); p.bd[i] = p.dbih[col] + p.dbhh[col]; return; }
  i -= 4096;
  if (i < 4194304) {  // mem_t[b][d][t] = bf16(memory[b][t][d])
    int b = i >> 17, rem = i & 131071, d = rem >> 8, t = rem & 255;
    p.mem_t[i] = f2bf(p.memory[((size_t)b * 256 + t) * 512 + d]);
    return;
  }
}

// ---------------- weight packing into MFMA B-fragment order ----------------
__global__ void pack_att(Params p) {
  int idx = blockIdx.x * 256 + threadIdx.x;
  if (idx >= 256 * 56 * 64) return;
  int l = idx & 63;
  int c = (idx >> 6) % 56;
  int T = idx / (56 * 64);
  int n = T * 16 + (l & 15);
  int col = (n & 3) * 1024 + (n >> 2);
  int kb = c * 32 + 8 * (l >> 4);
  bf16x8 v;
#pragma unroll
  for (int j = 0; j < 8; ++j) {
    int k = kb + j;
    float f = (k < 768) ? p.awih[(size_t)col * 768 + k] : p.awhh[(size_t)col * 1024 + k - 768];
    v[j] = (short)f2bf(f);
  }
  *(bf16x8*)(p.wpa + (size_t)idx * 8) = v;
}
__global__ void pack_dec(Params p) {
  int idx = blockIdx.x * 256 + threadIdx.x;
  if (idx >= 256 * 80 * 64) return;
  int l = idx & 63;
  int c = (idx >> 6) % 80;
  int T = idx / (80 * 64);
  int n = T * 16 + (l & 15);
  int col = (n & 3) * 1024 + (n >> 2);
  int kb = c * 32 + 8 * (l >> 4);
  bf16x8 v;
#pragma unroll
  for (int j = 0; j < 8; ++j) {
    int k = kb + j;
    float f = (k < 1536) ? p.dwih[(size_t)col * 1536 + k] : p.dwhh[(size_t)col * 1024 + k - 1536];
    v[j] = (short)f2bf(f);
  }
  *(bf16x8*)(p.wpd + (size_t)idx * 8) = v;
}

// ---------------- prenet ----------------
__global__ void prenet1_kernel(Params p) {
  __shared__ float din[8][80];
  int wg = blockIdx.x, tid = threadIdx.x;
  int r0 = wg * 8;
  for (int idx = tid; idx < 8 * 80; idx += 256) {
    int j = idx / 80, kk = idx % 80;
    int r = r0 + j; int t = r >> 5, b = r & 31;
    din[j][kk] = (t == 0) ? 0.f : p.dec_in[(size_t)b * 40000 + (size_t)kk * 500 + (t - 1)];
  }
  __syncthreads();
  float acc[8] = {0,0,0,0,0,0,0,0};
  for (int k = 0; k < 80; ++k) {
    float wv = p.w1t[k * 256 + tid];
#pragma unroll
    for (int j = 0; j < 8; ++j) acc[j] += din[j][k] * wv;
  }
  for (int j = 0; j < 8; ++j) {
    int r = r0 + j;
    unsigned e = (unsigned)r * 256u + tid;
    float mv = ((p.mm1[e >> 5] >> (e & 31)) & 1u) ? 2.0f : 0.0f;
    p.x1[(size_t)r * 256 + tid] = fmaxf(acc[j], 0.f) * mv;
  }
}
__global__ void prenet2_kernel(Params p) {
  __shared__ float rows[8][256];
  int wg = blockIdx.x, tid = threadIdx.x;
  int r0 = wg * 8;
  for (int idx = tid; idx < 8 * 256; idx += 256) {
    int j = idx >> 8, kk = idx & 255;
    rows[j][kk] = p.x1[(size_t)(r0 + j) * 256 + kk];
  }
  __syncthreads();
  float acc[8] = {0,0,0,0,0,0,0,0};
  for (int k = 0; k < 256; ++k) {
    float wv = p.w2t[k * 256 + tid];
#pragma unroll
    for (int j = 0; j < 8; ++j) acc[j] += rows[j][k] * wv;
  }
  for (int j = 0; j < 8; ++j) {
    int r = r0 + j;
    unsigned e = (unsigned)r * 256u + tid;
    float mv = ((p.mm2[e >> 5] >> (e & 31)) & 1u) ? 2.0f : 0.0f;
    p.pre_bf[(size_t)r * 256 + tid] = f2bf(fmaxf(acc[j], 0.f) * mv);
  }
}

// ---------------- processed_memory -> bf16 ----------------
__global__ void pm_kernel(Params p) {
  __shared__ float mrows[16][512];
  int wg = blockIdx.x;
  int b = wg >> 4, tc = wg & 15;
  int tid = threadIdx.x;
  int t0 = tc * 16;
  for (int idx = tid; idx < 16 * 512; idx += 128) {
    int i = idx >> 9, k = idx & 511;
    mrows[i][k] = p.memory[((size_t)b * 256 + t0 + i) * 512 + k];
  }
  __syncthreads();
  float acc[16];
#pragma unroll
  for (int i = 0; i < 16; ++i) acc[i] = 0.f;
  for (int k = 0; k < 512; ++k) {
    float wv = p.mwt[k * 128 + tid];
#pragma unroll
    for (int i = 0; i < 16; ++i) acc[i] += mrows[i][k] * wv;
  }
  for (int i = 0; i < 16; ++i)
    p.pm_bf[((size_t)b * 256 + t0 + i) * 128 + tid] = f2bf(acc[i]);
}

// ---------------- register-staged A-segment (NORMAL cached loads) ----------------
template<int LEN>
struct Seg {
  static constexpr int CPR = LEN / 8;          // 16B chunks per row
  static constexpr int N = (32 * CPR) / 512;   // chunks per thread (exact)
  u32x4 r[N];
  __device__ __forceinline__ void load(const unsigned short* src, int srcStride, int tid) {
#pragma unroll
    for (int i = 0; i < N; ++i) {
      int idx = tid + i * 512;
      int b = idx / CPR, c = idx % CPR;
      r[i] = ld16(src + (size_t)b * srcStride + c * 8);
    }
  }
  __device__ __forceinline__ void store(unsigned short* dst, int dstOff, int dstStride, int tid) {
#pragma unroll
    for (int i = 0; i < N; ++i) {
      int idx = tid + i * 512;
      int b = idx / CPR, c = idx % CPR;
      *(u32x4*)(dst + b * dstStride + dstOff + c * 8) = r[i];
    }
  }
};

__device__ __forceinline__ void drain_vm() {
  asm volatile("s_waitcnt vmcnt(0)" ::: "memory");
  __builtin_amdgcn_sched_barrier(0);
}

#define MFMA_BF16(a, b, c) __builtin_amdgcn_mfma_f32_16x16x32_bf16(a, b, c, 0, 0, 0)

// ---------------- GEMM: LDS-staged A (2 K-passes); weights in registers ----------------
template<int NC, int CPW, int P0J, bool ATT>
__device__ __forceinline__ void gemm_tile2(const Params& p, const bf16x8* bfa, const bf16x8* bfb,
                                           int lane, int v, int s,
                                           const unsigned short* ctxb_prev,
                                           const unsigned short* ahb_prev,
                                           const unsigned short* dhb_prev2,
                                           unsigned short* Abuf, float* pl, int tid) {
  const int arow = lane & 15;
  const int kgrp = (lane >> 4) * 8;
  f32x4 acc00 = {0,0,0,0}, acc01 = {0,0,0,0}, acc10 = {0,0,0,0}, acc11 = {0,0,0,0};

  // ---- pass 0: batch-issue all loads, drain once, write LDS ----
  const int RS0 = ATT ? 776 : 1288;   // row stride (elems), ≡8 mod 64 for bank spread
  if (ATT) {
    Seg<256> s0; Seg<512> s1;
    s0.load(p.pre_bf + (size_t)s * 32 * 256, 256, tid);
    s1.load(ctxb_prev, 512, tid);
    drain_vm();
    s0.store(Abuf, 0, RS0, tid);
    s1.store(Abuf, 256, RS0, tid);
  } else {
    Seg<1024> s0; Seg<256> s1;
    s0.load(ahb_prev, 1024, tid);
    s1.load(ctxb_prev, 512, tid);
    drain_vm();
    s0.store(Abuf, 0, RS0, tid);
    s1.store(Abuf, 1024, RS0, tid);
  }
  __syncthreads();
#pragma unroll
  for (int j = 0; j < P0J; ++j) {
    const int kc = (v + 8 * j) * 32;
    const int off = arow * RS0 + kc + kgrp;
    bf16x8 a0 = *(const bf16x8*)&Abuf[off];
    bf16x8 a1 = *(const bf16x8*)&Abuf[off + 16 * RS0];
    acc00 = MFMA_BF16(a0, bfa[j], acc00);
    acc01 = MFMA_BF16(a1, bfa[j], acc01);
    acc10 = MFMA_BF16(a0, bfb[j], acc10);
    acc11 = MFMA_BF16(a1, bfb[j], acc11);
  }
  __syncthreads();

  // ---- pass 1 ----
  const int RS1 = ATT ? 1032 : 1288;
  if (ATT) {
    Seg<1024> s0;
    s0.load(ahb_prev, 1024, tid);
    drain_vm();
    s0.store(Abuf, 0, RS1, tid);
  } else {
    Seg<256> s0; Seg<1024> s1;
    s0.load(ctxb_prev + 256, 512, tid);
    s1.load(dhb_prev2, 1024, tid);
    drain_vm();
    s0.store(Abuf, 0, RS1, tid);
    s1.store(Abuf, 256, RS1, tid);
  }
  __syncthreads();
  const int K1 = ATT ? 768 : 1280;
#pragma unroll
  for (int j = P0J; j < CPW; ++j) {
    const int kc = (v + 8 * j) * 32 - K1;
    const int off = arow * RS1 + kc + kgrp;
    bf16x8 a0 = *(const bf16x8*)&Abuf[off];
    bf16x8 a1 = *(const bf16x8*)&Abuf[off + 16 * RS1];
    acc00 = MFMA_BF16(a0, bfa[j], acc00);
    acc01 = MFMA_BF16(a1, bfa[j], acc01);
    acc10 = MFMA_BF16(a0, bfb[j], acc10);
    acc11 = MFMA_BF16(a1, bfb[j], acc11);
  }
  __syncthreads();   // Abuf reads done before pl overlay write

  const int po = (lane & 15) * 17 + (lane >> 4) * 4;
#pragma unroll
  for (int j = 0; j < 4; ++j) {
    pl[v * 1088 +   0 + po + j] = acc00[j];
    pl[v * 1088 + 272 + po + j] = acc01[j];
    pl[v * 1088 + 544 + po + j] = acc10[j];
    pl[v * 1088 + 816 + po + j] = acc11[j];
  }
}

// ---------------- barrier v4: slot barrier + ONE acquire-inv per WG ----------------
// Arrival = sc store (write-through). After release from the barrier, tid0
// executes fence(acquire,"agent") => buffer_inv ONCE, then __syncthreads orders
// all threads' subsequent NORMAL loads after the invalidate. Invalidate is
// cheap: weights/pjw are VGPR-resident; L2 refills ~2MB/XCD from memory-side.
template<bool MASTER>
__device__ __forceinline__ void gbar(const Params& p, int wg, int tid, unsigned bargen) {
  __syncthreads();   // drains vmcnt(0): all sc0sc1 state stores visible memory-side
  if (MASTER) {
    if (tid == 0) st_coh32(p.slots + wg * 32, bargen);
    for (;;) {
      int ok = 1;
      if (tid < 256) ok = (ld_coh32(p.slots + tid * 32) >= bargen) ? 1 : 0;
      if (__syncthreads_count(ok) == 512) break;
      __builtin_amdgcn_s_sleep(1);
    }
    if (tid < 8) st_coh32(p.flags + tid * 32, bargen);
    if (tid == 0) __builtin_amdgcn_fence(__ATOMIC_ACQUIRE, "agent");
    __syncthreads();
  } else {
    if (tid == 0) {
      st_coh32(p.slots + wg * 32, bargen);
      while (ld_coh32(p.flags + (wg & 7) * 32) < bargen)
        __builtin_amdgcn_s_sleep(2);
      __builtin_amdgcn_fence(__ATOMIC_ACQUIRE, "agent");
    }
    __syncthreads();
  }
}

// ---------------- the scan loop (R13 schedule), templated per WG role ----------------
template<bool IS_ATT, bool MASTER>
__device__ __forceinline__ void run_scan(const Params& p, int wg, int tid,
                                         unsigned short* Abuf, float* pl, float* gates,
                                         float* cst, float* aw_l, float* awc_l, float* sm,
                                         unsigned short* ahst, unsigned short* cxst,
                                         unsigned short* hst) {
  const int lane = tid & 63;
  const int v = tid >> 6;
  constexpr int NC  = IS_ATT ? 56 : 80;
  constexpr int CPW = IS_ATT ? 7 : 10;
  constexpr int P0J = IS_ATT ? 3 : 5;
  const int wgl = IS_ATT ? wg : (wg - 128);
  const int Tb  = wgl * 2;

  // Hoisted weight fragments: loaded ONCE, resident in VGPRs for all 500 steps.
  bf16x8 bfa[CPW], bfb[CPW];
  {
    const unsigned short* wp = IS_ATT ? p.wpa : p.wpd;
#pragma unroll
    for (int j = 0; j < CPW; ++j) {
      const int c = v + 8 * j;
      const unsigned short* bp = wp + ((size_t)(Tb * NC + c) * 64 + lane) * 8;
      bfa[j] = *(const bf16x8*)bp;
      bfb[j] = *(const bf16x8*)(bp + (size_t)NC * 64 * 8);
    }
  }

  // Hoisted mel projection rows (fp32), loaded once.
  float pjr[48];
  int melb = 0, melc7 = 0, melm0 = 0, melmc = 0;
  {
    if (wg >= 32) {
      int idx = wg - 32;
      melb = idx / 7; melc7 = idx % 7;
      melm0 = melc7 * 12; melmc = (melc7 == 6) ? 8 : 12;
      int mi = tid >> 5, kg = tid & 31;
      if (mi < melmc) {
        const float* pw = p.pjw + (size_t)(melm0 + mi) * 1536 + kg * 48;
#pragma unroll
        for (int j = 0; j < 48; ++j) pjr[j] = pw[j];
      }
    }
  }

  unsigned bargen = 0;

  for (int s = 0; s <= 500; ++s) {
    const int sb = s & 1;
    const unsigned short* ahb_prev  = sb ? p.ahb0 : p.ahb1;
    unsigned short*       ahb_cur   = sb ? p.ahb1 : p.ahb0;
    const unsigned short* dhb_prev2 = sb ? p.dhb1 : p.dhb0;
    unsigned short*       dhb_out   = sb ? p.dhb0 : p.dhb1;
    const unsigned short* ctxb_prev = sb ? p.ctxb0 : p.ctxb1;
    unsigned short*       ctxb_cur  = sb ? p.ctxb1 : p.ctxb0;

    const bool gemm_on = IS_ATT ? (s < 500) : (s >= 1);

    // ================= Phase X: LSTM gate GEMM =================
    if (gemm_on)
      gemm_tile2<NC, CPW, P0J, IS_ATT>(p, bfa, bfb, lane, v, s, ctxb_prev, ahb_prev, dhb_prev2, Abuf, pl, tid);
    __syncthreads();
    if (gemm_on) {
      const float* bias = IS_ATT ? p.ba : p.bd;
      const int nb32 = wgl * 32;
#pragma unroll
      for (int rep = 0; rep < 2; ++rep) {
        int o = rep * 512 + tid;
        int tile = o >> 9, half = (o >> 8) & 1, n = (o >> 4) & 15, brow = o & 15;
        int o2 = (tile * 2 + half) * 272 + n * 17 + brow;
        float acc = 0.f;
#pragma unroll
        for (int w = 0; w < 8; ++w) acc += pl[w * 1088 + o2];
        int n_local = tile * 16 + n;
        gates[n_local * 33 + half * 16 + brow] = acc + bias[nb32 + n_local];
      }
    }
    __syncthreads();
    if (gemm_on && tid < 256) {
      int u_local = tid >> 5, b = tid & 31;
      float gi = gates[(u_local * 4 + 0) * 33 + b];
      float gf = gates[(u_local * 4 + 1) * 33 + b];
      float gg = gates[(u_local * 4 + 2) * 33 + b];
      float go = gates[(u_local * 4 + 3) * 33 + b];
      float I = sigf(gi), F = sigf(gf), G = tanh_fast(gg), O = sigf(go);
      float c2 = F * cst[tid] + I * G;
      float h = O * tanh_fast(c2);
      cst[tid] = c2;
      int u = wgl * 8 + u_local;
      float mv;
      if (IS_ATT) {
        unsigned e = ((unsigned)s * 32 + b) * 1024u + u;
        mv = ((p.mma[e >> 5] >> (e & 31)) & 1u) ? (1.f / 0.9f) : 0.f;
      } else {
        unsigned e = ((unsigned)(s - 1) * 32 + b) * 1024u + u;
        mv = ((p.mmd[e >> 5] >> (e & 31)) & 1u) ? (1.f / 0.9f) : 0.f;
      }
      hst[tid] = f2bf(h * mv);
    }
    __syncthreads();
    if (gemm_on && tid < 128) {
      int j = tid >> 5, bb = tid & 31;
      unsigned lo = hst[j * 64 + bb], hi = hst[j * 64 + 32 + bb];
      unsigned val = lo | (hi << 16);
      unsigned short* basep = IS_ATT ? ahb_cur : dhb_out;
      int T8 = wgl * 8;
      st_coh32((unsigned*)(basep + (size_t)bb * 1024 + T8 + 2 * j), val);
    }

    gbar<MASTER>(p, wg, tid, ++bargen);

    // ================= Phase B =================
    if (IS_ATT && wg < 32) {
      if (s < 500) {
        const int b = wg;
        unsigned short* locT_bf = (unsigned short*)pl;          // 32 x 260 bf16
        float* ldwt_l = (float*)((char*)(void*)pl + 16640);     // 32 x 128 fp32
        {
          const float4* srcw = (const float4*)p.ldwt;
          float4* dstw = (float4*)ldwt_l;
          dstw[tid] = srcw[tid];
          dstw[tid + 512] = srcw[tid + 512];
        }
        if (tid < 256) {
          unsigned long long q = *((const unsigned long long*)(ahb_cur + (size_t)b * 1024) + tid);
          *(unsigned long long*)&ahst[tid * 4] = q;
        }
#pragma unroll
        for (int rep = 0; rep < 4; ++rep) {
          int qd = rep * 512 + tid;
          int f = qd >> 6, tq = (qd & 63) * 4;
          const float* wf = p.lcw + f * 62;
          float w[36]; float acc[4] = {0, 0, 0, 0};
#pragma unroll
          for (int j2 = 0; j2 < 9; ++j2) {
            float4 x = *(const float4*)&aw_l[tq + j2 * 4];
            w[j2*4] = x.x; w[j2*4+1] = x.y; w[j2*4+2] = x.z; w[j2*4+3] = x.w;
          }
#pragma unroll
          for (int k = 0; k < 31; ++k) {
            float cc = wf[k];
            acc[0] += w[k+1]*cc; acc[1] += w[k+2]*cc; acc[2] += w[k+3]*cc; acc[3] += w[k+4]*cc;
          }
#pragma unroll
          for (int j2 = 0; j2 < 9; ++j2) {
            float4 x = *(const float4*)&awc_l[tq + j2 * 4];
            w[j2*4] = x.x; w[j2*4+1] = x.y; w[j2*4+2] = x.z; w[j2*4+3] = x.w;
          }
#pragma unroll
          for (int k = 0; k < 31; ++k) {
            float cc = wf[31 + k];
            acc[0] += w[k+1]*cc; acc[1] += w[k+2]*cc; acc[2] += w[k+3]*cc; acc[3] += w[k+4]*cc;
          }
#pragma unroll
          for (int j2 = 0; j2 < 4; ++j2) locT_bf[f * 260 + tq + j2] = f2bf(acc[j2]);
        }
        __syncthreads();
        {
          int a = tid & 127, kq = tid >> 7;
          const unsigned short* qp = p.qw_bf + (size_t)a * 1024 + kq * 256;
          float acc = 0.f;
#pragma unroll 4
          for (int j = 0; j < 256; j += 8) {
            bf16x8 qv = *(const bf16x8*)(qp + j);
            bf16x8 av = *(const bf16x8*)&ahst[kq * 256 + j];
#pragma unroll
            for (int j2 = 0; j2 < 8; ++j2)
              acc += bf2f((unsigned short)av[j2]) * bf2f((unsigned short)qv[j2]);
          }
          sm[256 + kq * 128 + a] = acc;
          if (tid < 128) sm[128 + tid] = p.vw[tid];
        }
        __syncthreads();
        if (tid < 128) sm[tid] = sm[256 + tid] + sm[384 + tid] + sm[512 + tid] + sm[640 + tid];
        __syncthreads();
        {
          int t = tid & 255, h2 = tid >> 8;
          float lt[32];
#pragma unroll
          for (int f = 0; f < 32; ++f) lt[f] = bf2f(locT_bf[f * 260 + t]);
          const unsigned short* pmp = p.pm_bf + ((size_t)b * 256 + t) * 128;
          float e = 0.f;
#pragma unroll 2
          for (int ac = 0; ac < 16; ++ac) {
            int a0 = h2 * 64 + ac * 4;
            float4 l2 = {0, 0, 0, 0};
#pragma unroll
            for (int f = 0; f < 32; ++f) {
              float4 wv = *(const float4*)&ldwt_l[f * 128 + a0];
              l2.x += lt[f]*wv.x; l2.y += lt[f]*wv.y; l2.z += lt[f]*wv.z; l2.w += lt[f]*wv.w;
            }
            ushort4_t pv = *(const ushort4_t*)(pmp + a0);
            e += tanh_fast(sm[a0+0] + l2.x + bf2f(pv.x)) * sm[128+a0+0];
            e += tanh_fast(sm[a0+1] + l2.y + bf2f(pv.y)) * sm[128+a0+1];
            e += tanh_fast(sm[a0+2] + l2.z + bf2f(pv.z)) * sm[128+a0+2];
            e += tanh_fast(sm[a0+3] + l2.w + bf2f(pv.w)) * sm[128+a0+3];
          }
          sm[256 + h2 * 256 + t] = e;
        }
        __syncthreads();
        if (tid < 256) {
          float en = sm[256 + tid] + sm[512 + tid];
          float w = (tid < p.mlen[b]) ? __expf(en) : 0.f;
          sm[768 + tid] = w;
        }
        __syncthreads();
        if (tid < 32) {
          float sub = 0.f;
#pragma unroll
          for (int i = 0; i < 8; ++i) sub += sm[768 + tid * 8 + i];
          sm[256 + tid] = sub;
        }
        __syncthreads();
        if (tid == 0) {
          float S = 0.f;
#pragma unroll
          for (int i = 0; i < 32; ++i) S += sm[256 + i];
          sm[1281] = 1.f / S;
        }
        __syncthreads();
        if (tid < 256) {
          float awv = sm[768 + tid] * sm[1281];
          aw_l[16 + tid] = awv;
          awc_l[16 + tid] += awv;
          p.out[(size_t)AOFF + (size_t)b * 128000 + (size_t)s * 256 + tid] = awv;
          sm[1024 + tid] = awv;
        }
        __syncthreads();
        {
          // ctx via TRANSPOSED memory: per-thread contiguous 512B, wide loads
          const unsigned short* mt = p.mem_t + (size_t)b * 131072 + (size_t)tid * 256;
          float acc = 0.f;
#pragma unroll 8
          for (int t2 = 0; t2 < 256; t2 += 8) {
            bf16x8 mv = *(const bf16x8*)(mt + t2);
#pragma unroll
            for (int j2 = 0; j2 < 8; ++j2)
              acc += sm[1024 + t2 + j2] * bf2f((unsigned short)mv[j2]);
          }
          cxst[tid] = f2bf(acc);
        }
        __syncthreads();
        if (tid < 256) {
          unsigned val = (unsigned)cxst[2 * tid] | ((unsigned)cxst[2 * tid + 1] << 16);
          st_coh32((unsigned*)(ctxb_cur + (size_t)b * 512 + 2 * tid), val);
        }
      }
    } else if (wg >= 32) {
      if (s >= 1) {
        if (tid < 384) {
          unsigned long long q;
          if (tid < 256) q = *((const unsigned long long*)(dhb_out + (size_t)melb * 1024) + tid);
          else           q = *((const unsigned long long*)(ctxb_prev + (size_t)melb * 512) + (tid - 256));
          *(unsigned long long*)&ahst[tid * 4] = q;
        }
        __syncthreads();
        int mi = tid >> 5, kg = tid & 31;
        if (mi < melmc) {
          float acc = 0.f;
#pragma unroll
          for (int j = 0; j < 48; ++j) acc += bf2f(ahst[kg * 48 + j]) * pjr[j];
          sm[mi * 32 + kg] = acc;
        }
        if (melc7 == 6 && tid >= 384) {
          int kg2 = tid - 384;
          const float* gwp = p.gw + kg2 * 12;
          float acc = 0.f;
#pragma unroll
          for (int j = 0; j < 12; ++j) acc += bf2f(ahst[kg2 * 12 + j]) * gwp[j];
          sm[512 + kg2] = acc;
        }
        __syncthreads();
        if (tid < melmc) {
          float r = p.pjb[melm0 + tid];
#pragma unroll
          for (int j = 0; j < 32; ++j) r += sm[tid * 32 + j];
          p.out[(size_t)melb * 40000 + (size_t)(melm0 + tid) * 500 + (s - 1)] = r;
        }
        if (melc7 == 6 && tid == 384) {
          float r = p.gb[0];
#pragma unroll
          for (int j = 0; j < 128; ++j) r += sm[512 + j];
          p.out[(size_t)GOFF + (size_t)melb * 500 + (s - 1)] = r;
        }
      }
    }

    gbar<MASTER>(p, wg, tid, ++bargen);
  }
}

// ---------------- persistent scan kernel ----------------
__global__ void __launch_bounds__(512, 1) scan_kernel(Params p) {
  const int wg = blockIdx.x;
  const int tid = threadIdx.x;

  __shared__ __align__(16) unsigned short Abuf[32 * 1288];
  float* pl = (float*)Abuf;
  __shared__ float gates[32 * 33];
  __shared__ float cst[256];
  __shared__ float aw_l[292], awc_l[292];
  __shared__ float sm[1536];
  __shared__ unsigned short ahst[1536];
  __shared__ unsigned short cxst[512];
  __shared__ unsigned short hst[256];

  if (tid < 256) cst[tid] = 0.f;
  if (tid < 292) { aw_l[tid] = 0.f; awc_l[tid] = 0.f; }

  if (wg < 128) {
    if (wg == 32) run_scan<true, true >(p, wg, tid, Abuf, pl, gates, cst, aw_l, awc_l, sm, ahst, cxst, hst);
    else          run_scan<true, false>(p, wg, tid, Abuf, pl, gates, cst, aw_l, awc_l, sm, ahst, cxst, hst);
  } else {
    run_scan<false, false>(p, wg, tid, Abuf, pl, gates, cst, aw_l, awc_l, sm, ahst, cxst, hst);
  }
}

// ---------------- host ----------------
extern "C" void kernel_launch(void* const* d_in, const int* in_sizes, int n_in,
                              void* d_out, int out_size, void* d_ws, size_t ws_size,
                              hipStream_t stream) {
  Params p;
  p.memory = (const float*)d_in[0];
  p.dec_in = (const float*)d_in[1];
  p.mlen   = (const int*)d_in[2];
  p.pw1  = (const float*)d_in[3];
  p.pw2  = (const float*)d_in[4];
  p.awih = (const float*)d_in[5];
  p.awhh = (const float*)d_in[6];
  p.abih = (const float*)d_in[7];
  p.abhh = (const float*)d_in[8];
  p.qw   = (const float*)d_in[9];
  p.mw   = (const float*)d_in[10];
  p.vw   = (const float*)d_in[11];
  p.lcw  = (const float*)d_in[12];
  p.ldw  = (const float*)d_in[13];
  p.dwih = (const float*)d_in[14];
  p.dwhh = (const float*)d_in[15];
  p.dbih = (const float*)d_in[16];
  p.dbhh = (const float*)d_in[17];
  p.pjw  = (const float*)d_in[18];
  p.pjb  = (const float*)d_in[19];
  p.gw   = (const float*)d_in[20];
  p.gb   = (const float*)d_in[21];
  p.out  = (float*)d_out;

  char* cur = (char*)d_ws;
  auto allocf = [&](size_t n) { float* r = (float*)cur; cur += n * sizeof(float); return r; };
  auto allocs = [&](size_t n) { unsigned short* r = (unsigned short*)cur; cur += n * sizeof(unsigned short); return r; };
  // mutable state (memset each launch)
  p.ahb0 = allocs(32 * 1024); p.ahb1 = allocs(32 * 1024);
  p.dhb0 = allocs(32 * 1024); p.dhb1 = allocs(32 * 1024);
  p.ctxb0 = allocs(32 * 512); p.ctxb1 = allocs(32 * 512);
  p.slots = (unsigned*)cur; cur += 256 * 32 * sizeof(unsigned);  // 256 slots, 128B lines
  p.flags = (unsigned*)cur; cur += 8 * 32 * sizeof(unsigned);    // 8 flag copies
  size_t state_bytes = (size_t)(cur - (char*)d_ws);
  // static
  p.x1   = allocf((size_t)500 * 32 * 256);
  p.w1t  = allocf(80 * 256);
  p.w2t  = allocf(256 * 256);
  p.mwt  = allocf(512 * 128);
  p.ldwt = allocf(32 * 128);
  p.ba   = allocf(4096);
  p.bd   = allocf(4096);
  p.pre_bf  = allocs((size_t)500 * 32 * 256);
  p.pm_bf   = allocs((size_t)32 * 256 * 128);
  p.mem_t   = allocs((size_t)32 * 512 * 256);
  p.qw_bf   = allocs(128 * 1024);
  p.wpa     = allocs((size_t)256 * 56 * 64 * 8);
  p.wpd     = allocs((size_t)256 * 80 * 64 * 8);
  p.mma = (unsigned*)cur; cur += 512000u * 4;
  p.mmd = (unsigned*)cur; cur += 512000u * 4;
  p.mm1 = (unsigned*)cur; cur += 128256u * 4;
  p.mm2 = (unsigned*)cur; cur += 128256u * 4;

  (void)hipMemsetAsync(d_ws, 0, state_bytes, stream);

  unsigned k[8];
  {
    unsigned o0, o1;
    tf_block(0u, 1u, 0u, 0u, o0, o1); k[0] = o0; k[1] = o1;
    tf_block(0u, 1u, 0u, 1u, o0, o1); k[2] = o0; k[3] = o1;
    tf_block(0u, 1u, 0u, 2u, o0, o1); k[4] = o0; k[5] = o1;
    tf_block(0u, 1u, 0u, 3u, o0, o1); k[6] = o0; k[7] = o1;
  }

  maskgen_kernel<<<(1280512 + 255) / 256, 256, 0, stream>>>(p, k[0], k[1], k[2], k[3], k[4], k[5], k[6], k[7]);
  prep_misc<<<(4489216 + 255) / 256, 256, 0, stream>>>(p);
  pack_att<<<(917504 + 255) / 256, 256, 0, stream>>>(p);
  pack_dec<<<(1310720 + 255) / 256, 256, 0, stream>>>(p);
  prenet1_kernel<<<2000, 256, 0, stream>>>(p);
  prenet2_kernel<<<2000, 256, 0, stream>>>(p);
  pm_kernel<<<512, 128, 0, stream>>>(p);

  void* args[] = { (void*)&p };
  (void)hipLaunchCooperativeKernel((const void*)scan_kernel, dim3(256), dim3(512), args, 0, stream);
}

// Round 18
// 34765.503 us; speedup vs baseline: 1.0798x; 1.0798x over previous
//
#include <hip/hip_runtime.h>
#include <math.h>
#include <string.h>

#define TOUT 500
#define AOFF 1296000
#define GOFF 1280000
#define TF_BITS_XOR 1

typedef float f32x4 __attribute__((ext_vector_type(4)));
typedef short bf16x8 __attribute__((ext_vector_type(8)));
typedef unsigned short ushort4_t __attribute__((ext_vector_type(4)));
typedef unsigned u32x4 __attribute__((ext_vector_type(4)));

struct Params {
  const float *memory, *dec_in, *pw1, *pw2, *awih, *awhh, *abih, *abhh;
  const float *qw, *mw, *vw, *lcw, *ldw, *dwih, *dwhh, *dbih, *dbhh;
  const float *pjw, *pjb, *gw, *gb;
  const int* mlen;
  float* out;
  // mutable cross-WG state (bf16), memset each launch
  unsigned short *ahb0, *ahb1, *dhb0, *dhb1, *ctxb0, *ctxb1;
  unsigned *slots;    // [256] stride 32 words (128B lines)
  unsigned *abf;      // [8]  att-domain barrier flags
  unsigned *dbf;      // [8]  dec-domain barrier flags
  unsigned *attflag;  // [8]  att progress (stores s+1 after attention_s)
  unsigned *decflag;  // [8]  dec progress (stores i+1 after mel_i)
  // static precomputed
  float *x1, *w1t, *w2t, *mwt, *ldwt, *ba, *bd;
  unsigned short *pre_bf, *pm_bf, *mem_t, *qw_bf, *wpa, *wpd;
  unsigned *mma, *mmd, *mm1, *mm2;
};

// ---------------- threefry2x32 (matches jax partitionable path) ----------------
__host__ __device__ inline void tf_block(unsigned k0, unsigned k1, unsigned x0, unsigned x1,
                                         unsigned& o0, unsigned& o1) {
  unsigned ks2 = k0 ^ k1 ^ 0x1BD11BDAu;
  x0 += k0; x1 += k1;
#define TFR(r) { x0 += x1; x1 = (x1 << r) | (x1 >> (32 - r)); x1 ^= x0; }
  TFR(13) TFR(15) TFR(26) TFR(6)
  x0 += k1;  x1 += ks2 + 1u;
  TFR(17) TFR(29) TFR(16) TFR(24)
  x0 += ks2; x1 += k0 + 2u;
  TFR(13) TFR(15) TFR(26) TFR(6)
  x0 += k0;  x1 += k1 + 3u;
  TFR(17) TFR(29) TFR(16) TFR(24)
  x0 += k1;  x1 += ks2 + 4u;
  TFR(13) TFR(15) TFR(26) TFR(6)
  x0 += ks2; x1 += k0 + 5u;
#undef TFR
  o0 = x0; o1 = x1;
}

__device__ inline float sigf(float x) { return 1.f / (1.f + __expf(-x)); }
__device__ inline float tanh_fast(float x) {
  float ax = fabsf(x);
  float t = __expf(-2.f * ax);
  float r = (1.f - t) / (1.f + t);
  return copysignf(r, x);
}
__device__ inline unsigned short f2bf(float f) {
  unsigned u = __float_as_uint(f);
  unsigned r = (u + 0x7FFFu + ((u >> 16) & 1u)) >> 16;
  return (unsigned short)r;
}
__device__ inline float bf2f(unsigned short u) {
  return __uint_as_float((unsigned)u << 16);
}

// coherent state access — SYSTEM scope => sc0 sc1 => L2-bypass (R15 model).
__device__ inline unsigned long long ld_coh64(const void* ptr) {
  return __hip_atomic_load((unsigned long long*)ptr, __ATOMIC_RELAXED, __HIP_MEMORY_SCOPE_SYSTEM);
}
__device__ inline unsigned ld_coh32(const unsigned* ptr) {
  return __hip_atomic_load(ptr, __ATOMIC_RELAXED, __HIP_MEMORY_SCOPE_SYSTEM);
}
__device__ inline void st_coh32(unsigned* ptr, unsigned v) {
  __hip_atomic_store(ptr, v, __ATOMIC_RELAXED, __HIP_MEMORY_SCOPE_SYSTEM);
}

// 16B load issued without implicit waitcnt pairing — batch-issue, drain once.
template<bool COH>
__device__ __forceinline__ u32x4 ld16(const void* ptr) {
  u32x4 r;
  if constexpr (COH)
    asm volatile("global_load_dwordx4 %0, %1, off sc0 sc1" : "=v"(r) : "v"(ptr));
  else
    asm volatile("global_load_dwordx4 %0, %1, off" : "=v"(r) : "v"(ptr));
  return r;
}

#define LD4(p) (*(const float4*)(p))

// ---------------- mask generation (bit-packed) ----------------
__global__ void maskgen_kernel(Params p, unsigned k1a, unsigned k1b, unsigned k2a, unsigned k2b,
                               unsigned k3a, unsigned k3b, unsigned k4a, unsigned k4b) {
  int t = blockIdx.x * 256 + threadIdx.x;
  unsigned ka, kb; unsigned* dst; float pp;
  if (t < 512000)       { ka = k3a; kb = k3b; dst = p.mma; pp = 0.9f; }
  else if (t < 1024000) { t -= 512000;  ka = k4a; kb = k4b; dst = p.mmd; pp = 0.9f; }
  else if (t < 1152256) { t -= 1024000; ka = k1a; kb = k1b; dst = p.mm1; pp = 0.5f; }
  else if (t < 1280512) { t -= 1152256; ka = k2a; kb = k2b; dst = p.mm2; pp = 0.5f; }
  else return;
  unsigned word = 0u;
  for (int i = 0; i < 32; ++i) {
    unsigned o0, o1;
    tf_block(ka, kb, 0u, (unsigned)t * 32u + (unsigned)i, o0, o1);
#if TF_BITS_XOR
    unsigned bits = o0 ^ o1;
#else
    unsigned bits = o0;
#endif
    unsigned fb = (bits >> 9) | 0x3f800000u;
    float u = __uint_as_float(fb) - 1.0f;
    if (u < pp) word |= (1u << i);
  }
  dst[t] = word;
}

// ---------------- misc static prep ----------------
__global__ void prep_misc(Params p) {
  int i = blockIdx.x * 256 + threadIdx.x;
  if (i < 20480) { int k = i >> 8, u = i & 255; p.w1t[i] = p.pw1[u * 80 + k]; return; }
  i -= 20480;
  if (i < 65536) { int k = i >> 8, u = i & 255; p.w2t[i] = p.pw2[u * 256 + k]; return; }
  i -= 65536;
  if (i < 65536) { int k = i >> 7, a = i & 127; p.mwt[i] = p.mw[a * 512 + k]; return; }
  i -= 65536;
  if (i < 131072) { p.qw_bf[i] = f2bf(p.qw[i]); return; }
  i -= 131072;
  if (i < 4096) { int f = i >> 7, a = i & 127; p.ldwt[i] = p.ldw[a * 32 + f]; return; }
  i -= 4096;
  if (i < 4096) { int col = (i & 3) * 1024 + (i >> 2); p.ba[i] = p.abih[col] + p.abhh[col]; return; }
  i -= 4096;
  if (i < 4096) { int col = (i & 3) * 1024 + (i >> 2); p.bd[i] = p.dbih[col] + p.dbhh[col]; return; }
  i -= 4096;
  if (i < 4194304) {  // mem_t[b][d][t] = bf16(memory[b][t][d])
    int b = i >> 17, rem = i & 131071, d = rem >> 8, t = rem & 255;
    p.mem_t[i] = f2bf(p.memory[((size_t)b * 256 + t) * 512 + d]);
    return;
  }
}

// ---------------- weight packing into MFMA B-fragment order ----------------
__global__ void pack_att(Params p) {
  int idx = blockIdx.x * 256 + threadIdx.x;
  if (idx >= 256 * 56 * 64) return;
  int l = idx & 63;
  int c = (idx >> 6) % 56;
  int T = idx / (56 * 64);
  int n = T * 16 + (l & 15);
  int col = (n & 3) * 1024 + (n >> 2);
  int kb = c * 32 + 8 * (l >> 4);
  bf16x8 v;
#pragma unroll
  for (int j = 0; j < 8; ++j) {
    int k = kb + j;
    float f = (k < 768) ? p.awih[(size_t)col * 768 + k] : p.awhh[(size_t)col * 1024 + k - 768];
    v[j] = (short)f2bf(f);
  }
  *(bf16x8*)(p.wpa + (size_t)idx * 8) = v;
}
__global__ void pack_dec(Params p) {
  int idx = blockIdx.x * 256 + threadIdx.x;
  if (idx >= 256 * 80 * 64) return;
  int l = idx & 63;
  int c = (idx >> 6) % 80;
  int T = idx / (80 * 64);
  int n = T * 16 + (l & 15);
  int col = (n & 3) * 1024 + (n >> 2);
  int kb = c * 32 + 8 * (l >> 4);
  bf16x8 v;
#pragma unroll
  for (int j = 0; j < 8; ++j) {
    int k = kb + j;
    float f = (k < 1536) ? p.dwih[(size_t)col * 1536 + k] : p.dwhh[(size_t)col * 1024 + k - 1536];
    v[j] = (short)f2bf(f);
  }
  *(bf16x8*)(p.wpd + (size_t)idx * 8) = v;
}

// ---------------- prenet ----------------
__global__ void prenet1_kernel(Params p) {
  __shared__ float din[8][80];
  int wg = blockIdx.x, tid = threadIdx.x;
  int r0 = wg * 8;
  for (int idx = tid; idx < 8 * 80; idx += 256) {
    int j = idx / 80, kk = idx % 80;
    int r = r0 + j; int t = r >> 5, b = r & 31;
    din[j][kk] = (t == 0) ? 0.f : p.dec_in[(size_t)b * 40000 + (size_t)kk * 500 + (t - 1)];
  }
  __syncthreads();
  float acc[8] = {0,0,0,0,0,0,0,0};
  for (int k = 0; k < 80; ++k) {
    float wv = p.w1t[k * 256 + tid];
#pragma unroll
    for (int j = 0; j < 8; ++j) acc[j] += din[j][k] * wv;
  }
  for (int j = 0; j < 8; ++j) {
    int r = r0 + j;
    unsigned e = (unsigned)r * 256u + tid;
    float mv = ((p.mm1[e >> 5] >> (e & 31)) & 1u) ? 2.0f : 0.0f;
    p.x1[(size_t)r * 256 + tid] = fmaxf(acc[j], 0.f) * mv;
  }
}
__global__ void prenet2_kernel(Params p) {
  __shared__ float rows[8][256];
  int wg = blockIdx.x, tid = threadIdx.x;
  int r0 = wg * 8;
  for (int idx = tid; idx < 8 * 256; idx += 256) {
    int j = idx >> 8, kk = idx & 255;
    rows[j][kk] = p.x1[(size_t)(r0 + j) * 256 + kk];
  }
  __syncthreads();
  float acc[8] = {0,0,0,0,0,0,0,0};
  for (int k = 0; k < 256; ++k) {
    float wv = p.w2t[k * 256 + tid];
#pragma unroll
    for (int j = 0; j < 8; ++j) acc[j] += rows[j][k] * wv;
  }
  for (int j = 0; j < 8; ++j) {
    int r = r0 + j;
    unsigned e = (unsigned)r * 256u + tid;
    float mv = ((p.mm2[e >> 5] >> (e & 31)) & 1u) ? 2.0f : 0.0f;
    p.pre_bf[(size_t)r * 256 + tid] = f2bf(fmaxf(acc[j], 0.f) * mv);
  }
}

// ---------------- processed_memory -> bf16 ----------------
__global__ void pm_kernel(Params p) {
  __shared__ float mrows[16][512];
  int wg = blockIdx.x;
  int b = wg >> 4, tc = wg & 15;
  int tid = threadIdx.x;
  int t0 = tc * 16;
  for (int idx = tid; idx < 16 * 512; idx += 128) {
    int i = idx >> 9, k = idx & 511;
    mrows[i][k] = p.memory[((size_t)b * 256 + t0 + i) * 512 + k];
  }
  __syncthreads();
  float acc[16];
#pragma unroll
  for (int i = 0; i < 16; ++i) acc[i] = 0.f;
  for (int k = 0; k < 512; ++k) {
    float wv = p.mwt[k * 128 + tid];
#pragma unroll
    for (int i = 0; i < 16; ++i) acc[i] += mrows[i][k] * wv;
  }
  for (int i = 0; i < 16; ++i)
    p.pm_bf[((size_t)b * 256 + t0 + i) * 128 + tid] = f2bf(acc[i]);
}

// ---------------- register-staged A-segment ----------------
template<int LEN, bool COH>
struct Seg {
  static constexpr int CPR = LEN / 8;
  static constexpr int N = (32 * CPR) / 512;
  u32x4 r[N];
  __device__ __forceinline__ void load(const unsigned short* src, int srcStride, int tid) {
#pragma unroll
    for (int i = 0; i < N; ++i) {
      int idx = tid + i * 512;
      int b = idx / CPR, c = idx % CPR;
      r[i] = ld16<COH>(src + (size_t)b * srcStride + c * 8);
    }
  }
  __device__ __forceinline__ void store(unsigned short* dst, int dstOff, int dstStride, int tid) {
#pragma unroll
    for (int i = 0; i < N; ++i) {
      int idx = tid + i * 512;
      int b = idx / CPR, c = idx % CPR;
      *(u32x4*)(dst + b * dstStride + dstOff + c * 8) = r[i];
    }
  }
};

__device__ __forceinline__ void drain_vm() {
  asm volatile("s_waitcnt vmcnt(0)" ::: "memory");
  __builtin_amdgcn_sched_barrier(0);
}

#define MFMA_BF16(a, b, c) __builtin_amdgcn_mfma_f32_16x16x32_bf16(a, b, c, 0, 0, 0)

// ---------------- LSTM: LDS-staged A (2 K-passes); weights in registers ----------------
template<int NC, int CPW, int P0J, bool ATT>
__device__ __forceinline__ void gemm_tile2(const Params& p, const bf16x8* bfa, const bf16x8* bfb,
                                           int lane, int v, int s,
                                           const unsigned short* ctxb_in,
                                           const unsigned short* ahb_in,
                                           const unsigned short* dhb_in,
                                           unsigned short* Abuf, float* pl, int tid) {
  const int arow = lane & 15;
  const int kgrp = (lane >> 4) * 8;
  f32x4 acc00 = {0,0,0,0}, acc01 = {0,0,0,0}, acc10 = {0,0,0,0}, acc11 = {0,0,0,0};

  // ---- pass 0 ----
  const int RS0 = ATT ? 776 : 1288;
  if (ATT) {
    Seg<256, false> s0; Seg<512, true> s1;
    s0.load(p.pre_bf + (size_t)s * 32 * 256, 256, tid);
    s1.load(ctxb_in, 512, tid);
    drain_vm();
    s0.store(Abuf, 0, RS0, tid);
    s1.store(Abuf, 256, RS0, tid);
  } else {
    Seg<1024, true> s0; Seg<256, true> s1;
    s0.load(ahb_in, 1024, tid);
    s1.load(ctxb_in, 512, tid);
    drain_vm();
    s0.store(Abuf, 0, RS0, tid);
    s1.store(Abuf, 1024, RS0, tid);
  }
  __syncthreads();
#pragma unroll
  for (int j = 0; j < P0J; ++j) {
    const int kc = (v + 8 * j) * 32;
    const int off = arow * RS0 + kc + kgrp;
    bf16x8 a0 = *(const bf16x8*)&Abuf[off];
    bf16x8 a1 = *(const bf16x8*)&Abuf[off + 16 * RS0];
    acc00 = MFMA_BF16(a0, bfa[j], acc00);
    acc01 = MFMA_BF16(a1, bfa[j], acc01);
    acc10 = MFMA_BF16(a0, bfb[j], acc10);
    acc11 = MFMA_BF16(a1, bfb[j], acc11);
  }
  __syncthreads();

  // ---- pass 1 ----
  const int RS1 = ATT ? 1032 : 1288;
  if (ATT) {
    Seg<1024, true> s0;
    s0.load(ahb_in, 1024, tid);
    drain_vm();
    s0.store(Abuf, 0, RS1, tid);
  } else {
    Seg<256, true> s0; Seg<1024, true> s1;
    s0.load(ctxb_in + 256, 512, tid);
    s1.load(dhb_in, 1024, tid);
    drain_vm();
    s0.store(Abuf, 0, RS1, tid);
    s1.store(Abuf, 256, RS1, tid);
  }
  __syncthreads();
  const int K1 = ATT ? 768 : 1280;
#pragma unroll
  for (int j = P0J; j < CPW; ++j) {
    const int kc = (v + 8 * j) * 32 - K1;
    const int off = arow * RS1 + kc + kgrp;
    bf16x8 a0 = *(const bf16x8*)&Abuf[off];
    bf16x8 a1 = *(const bf16x8*)&Abuf[off + 16 * RS1];
    acc00 = MFMA_BF16(a0, bfa[j], acc00);
    acc01 = MFMA_BF16(a1, bfa[j], acc01);
    acc10 = MFMA_BF16(a0, bfb[j], acc10);
    acc11 = MFMA_BF16(a1, bfb[j], acc11);
  }
  __syncthreads();

  const int po = (lane & 15) * 17 + (lane >> 4) * 4;
#pragma unroll
  for (int j = 0; j < 4; ++j) {
    pl[v * 1088 +   0 + po + j] = acc00[j];
    pl[v * 1088 + 272 + po + j] = acc01[j];
    pl[v * 1088 + 544 + po + j] = acc10[j];
    pl[v * 1088 + 816 + po + j] = acc11[j];
  }
}

// gate reduce + cell + h-store (shared by both domains)
template<bool ATT>
__device__ __forceinline__ void lstm_tail(const Params& p, int wgl, int tid, unsigned step,
                                          unsigned short* hout, float* pl, float* gates,
                                          float* cst, unsigned short* hst) {
  __syncthreads();
  {
    const float* bias = ATT ? p.ba : p.bd;
    const int nb32 = wgl * 32;
#pragma unroll
    for (int rep = 0; rep < 2; ++rep) {
      int o = rep * 512 + tid;
      int tile = o >> 9, half = (o >> 8) & 1, n = (o >> 4) & 15, brow = o & 15;
      int o2 = (tile * 2 + half) * 272 + n * 17 + brow;
      float acc = 0.f;
#pragma unroll
      for (int w = 0; w < 8; ++w) acc += pl[w * 1088 + o2];
      int n_local = tile * 16 + n;
      gates[n_local * 33 + half * 16 + brow] = acc + bias[nb32 + n_local];
    }
  }
  __syncthreads();
  if (tid < 256) {
    int u_local = tid >> 5, b = tid & 31;
    float gi = gates[(u_local * 4 + 0) * 33 + b];
    float gf = gates[(u_local * 4 + 1) * 33 + b];
    float gg = gates[(u_local * 4 + 2) * 33 + b];
    float go = gates[(u_local * 4 + 3) * 33 + b];
    float I = sigf(gi), F = sigf(gf), G = tanh_fast(gg), O = sigf(go);
    float c2 = F * cst[tid] + I * G;
    float h = O * tanh_fast(c2);
    cst[tid] = c2;
    int u = wgl * 8 + u_local;
    const unsigned* maskw = ATT ? p.mma : p.mmd;
    unsigned e = (step * 32 + (unsigned)b) * 1024u + (unsigned)u;
    float mv = ((maskw[e >> 5] >> (e & 31)) & 1u) ? (1.f / 0.9f) : 0.f;
    hst[tid] = f2bf(h * mv);
  }
  __syncthreads();
  if (tid < 128) {
    int j = tid >> 5, bb = tid & 31;
    unsigned lo = hst[j * 64 + bb], hi = hst[j * 64 + 32 + bb];
    unsigned val = lo | (hi << 16);
    int T8 = wgl * 8;
    st_coh32((unsigned*)(hout + (size_t)bb * 1024 + T8 + 2 * j), val);
  }
}

// ---------------- per-domain slot barrier (128 WGs) ----------------
// base: slot index base (0 for att, 128 for dec). flg: 8-copy flag array.
template<bool MASTER>
__device__ __forceinline__ void dbar(const Params& p, unsigned* flg, int base, int wg, int tid, unsigned gen) {
  __syncthreads();
  if (MASTER) {
    if (tid == 0) st_coh32(p.slots + (base + (wg & 127)) * 32, gen);
    for (;;) {
      int ok = 1;
      if (tid < 128) ok = (ld_coh32(p.slots + (base + tid) * 32) >= gen) ? 1 : 0;
      if (__syncthreads_count(ok) == 512) break;
      __builtin_amdgcn_s_sleep(1);
    }
    if (tid < 8) st_coh32(flg + tid * 32, gen);
  } else {
    if (tid == 0) {
      st_coh32(p.slots + (base + (wg & 127)) * 32, gen);
      while (ld_coh32(flg + (wg & 7) * 32) < gen)
        __builtin_amdgcn_s_sleep(2);
    }
    __syncthreads();
  }
}

// ---------------- ATT domain: wg 0..127 (master = 32) ----------------
template<bool MASTER>
__device__ void run_att(const Params& p, int wg, int tid,
                        unsigned short* Abuf, float* pl, float* gates,
                        float* cst, float* aw_l, float* awc_l, float* sm,
                        unsigned short* ahst, unsigned short* cxst, unsigned short* hst) {
  const int lane = tid & 63;
  const int v = tid >> 6;
  const int Tb = wg * 2;

  bf16x8 bfa[7], bfb[7];
#pragma unroll
  for (int j = 0; j < 7; ++j) {
    const int c = v + 8 * j;
    const unsigned short* bp = p.wpa + ((size_t)(Tb * 56 + c) * 64 + lane) * 8;
    bfa[j] = *(const bf16x8*)bp;
    bfb[j] = *(const bf16x8*)(bp + (size_t)56 * 64 * 8);
  }

  unsigned gen = 0;
  for (int s = 0; s < 500; ++s) {
    const int sb = s & 1;
    const unsigned short* ahb_prev = sb ? p.ahb0 : p.ahb1;
    unsigned short*       ahb_cur  = sb ? p.ahb1 : p.ahb0;
    const unsigned short* ctxb_prev = sb ? p.ctxb0 : p.ctxb1;
    unsigned short*       ctxb_cur  = sb ? p.ctxb1 : p.ctxb0;

    // throttle: don't overwrite 2-deep buffers until dec finished step s-2
    if (tid == 0) {
      while ((int)ld_coh32(p.decflag + (wg & 7) * 32) < s - 1)
        __builtin_amdgcn_s_sleep(4);
    }
    __syncthreads();

    // attLSTM_s
    gemm_tile2<56, 7, 3, true>(p, bfa, bfb, lane, v, s, ctxb_prev, ahb_prev, nullptr, Abuf, pl, tid);
    lstm_tail<true>(p, wg, tid, (unsigned)s, ahb_cur, pl, gates, cst, hst);

    dbar<MASTER>(p, p.abf, 0, wg, tid, ++gen);

    // attention_s (wg < 32)
    if (wg < 32) {
      const int b = wg;
      unsigned short* locT_bf = (unsigned short*)pl;
      float* ldwt_l = (float*)((char*)(void*)pl + 16640);
      {
        const float4* srcw = (const float4*)p.ldwt;
        float4* dstw = (float4*)ldwt_l;
        dstw[tid] = srcw[tid];
        dstw[tid + 512] = srcw[tid + 512];
      }
      if (tid < 256) {
        unsigned long long q = ld_coh64((const unsigned long long*)(ahb_cur + (size_t)b * 1024) + tid);
        *(unsigned long long*)&ahst[tid * 4] = q;
      }
#pragma unroll
      for (int rep = 0; rep < 4; ++rep) {
        int qd = rep * 512 + tid;
        int f = qd >> 6, tq = (qd & 63) * 4;
        const float* wf = p.lcw + f * 62;
        float w[36]; float acc[4] = {0, 0, 0, 0};
#pragma unroll
        for (int j2 = 0; j2 < 9; ++j2) {
          float4 x = *(const float4*)&aw_l[tq + j2 * 4];
          w[j2*4] = x.x; w[j2*4+1] = x.y; w[j2*4+2] = x.z; w[j2*4+3] = x.w;
        }
#pragma unroll
        for (int k = 0; k < 31; ++k) {
          float cc = wf[k];
          acc[0] += w[k+1]*cc; acc[1] += w[k+2]*cc; acc[2] += w[k+3]*cc; acc[3] += w[k+4]*cc;
        }
#pragma unroll
        for (int j2 = 0; j2 < 9; ++j2) {
          float4 x = *(const float4*)&awc_l[tq + j2 * 4];
          w[j2*4] = x.x; w[j2*4+1] = x.y; w[j2*4+2] = x.z; w[j2*4+3] = x.w;
        }
#pragma unroll
        for (int k = 0; k < 31; ++k) {
          float cc = wf[31 + k];
          acc[0] += w[k+1]*cc; acc[1] += w[k+2]*cc; acc[2] += w[k+3]*cc; acc[3] += w[k+4]*cc;
        }
#pragma unroll
        for (int j2 = 0; j2 < 4; ++j2) locT_bf[f * 260 + tq + j2] = f2bf(acc[j2]);
      }
      __syncthreads();
      {
        int a = tid & 127, kq = tid >> 7;
        const unsigned short* qp = p.qw_bf + (size_t)a * 1024 + kq * 256;
        float acc = 0.f;
#pragma unroll 4
        for (int j = 0; j < 256; j += 8) {
          bf16x8 qv = *(const bf16x8*)(qp + j);
          bf16x8 av = *(const bf16x8*)&ahst[kq * 256 + j];
#pragma unroll
          for (int j2 = 0; j2 < 8; ++j2)
            acc += bf2f((unsigned short)av[j2]) * bf2f((unsigned short)qv[j2]);
        }
        sm[256 + kq * 128 + a] = acc;
        if (tid < 128) sm[128 + tid] = p.vw[tid];
      }
      __syncthreads();
      if (tid < 128) sm[tid] = sm[256 + tid] + sm[384 + tid] + sm[512 + tid] + sm[640 + tid];
      __syncthreads();
      {
        int t = tid & 255, h2 = tid >> 8;
        float lt[32];
#pragma unroll
        for (int f = 0; f < 32; ++f) lt[f] = bf2f(locT_bf[f * 260 + t]);
        const unsigned short* pmp = p.pm_bf + ((size_t)b * 256 + t) * 128;
        float e = 0.f;
#pragma unroll 2
        for (int ac = 0; ac < 16; ++ac) {
          int a0 = h2 * 64 + ac * 4;
          float4 l2 = {0, 0, 0, 0};
#pragma unroll
          for (int f = 0; f < 32; ++f) {
            float4 wv = *(const float4*)&ldwt_l[f * 128 + a0];
            l2.x += lt[f]*wv.x; l2.y += lt[f]*wv.y; l2.z += lt[f]*wv.z; l2.w += lt[f]*wv.w;
          }
          ushort4_t pv = *(const ushort4_t*)(pmp + a0);
          e += tanh_fast(sm[a0+0] + l2.x + bf2f(pv.x)) * sm[128+a0+0];
          e += tanh_fast(sm[a0+1] + l2.y + bf2f(pv.y)) * sm[128+a0+1];
          e += tanh_fast(sm[a0+2] + l2.z + bf2f(pv.z)) * sm[128+a0+2];
          e += tanh_fast(sm[a0+3] + l2.w + bf2f(pv.w)) * sm[128+a0+3];
        }
        sm[256 + h2 * 256 + t] = e;
      }
      __syncthreads();
      if (tid < 256) {
        float en = sm[256 + tid] + sm[512 + tid];
        float w = (tid < p.mlen[b]) ? __expf(en) : 0.f;
        sm[768 + tid] = w;
      }
      __syncthreads();
      if (tid < 32) {
        float sub = 0.f;
#pragma unroll
        for (int i2 = 0; i2 < 8; ++i2) sub += sm[768 + tid * 8 + i2];
        sm[256 + tid] = sub;
      }
      __syncthreads();
      if (tid == 0) {
        float S = 0.f;
#pragma unroll
        for (int i2 = 0; i2 < 32; ++i2) S += sm[256 + i2];
        sm[1281] = 1.f / S;
      }
      __syncthreads();
      if (tid < 256) {
        float awv = sm[768 + tid] * sm[1281];
        aw_l[16 + tid] = awv;
        awc_l[16 + tid] += awv;
        p.out[(size_t)AOFF + (size_t)b * 128000 + (size_t)s * 256 + tid] = awv;
        sm[1024 + tid] = awv;
      }
      __syncthreads();
      {
        const unsigned short* mt = p.mem_t + (size_t)b * 131072 + (size_t)tid * 256;
        float acc = 0.f;
#pragma unroll 8
        for (int t2 = 0; t2 < 256; t2 += 8) {
          bf16x8 mv = *(const bf16x8*)(mt + t2);
#pragma unroll
          for (int j2 = 0; j2 < 8; ++j2)
            acc += sm[1024 + t2 + j2] * bf2f((unsigned short)mv[j2]);
        }
        cxst[tid] = f2bf(acc);
      }
      __syncthreads();
      if (tid < 256) {
        unsigned val = (unsigned)cxst[2 * tid] | ((unsigned)cxst[2 * tid + 1] << 16);
        st_coh32((unsigned*)(ctxb_cur + (size_t)b * 512 + 2 * tid), val);
      }
    }

    dbar<MASTER>(p, p.abf, 0, wg, tid, ++gen);

    // publish: step s fully done (ah_s, ctx_s visible)
    if (MASTER && tid < 8) st_coh32(p.attflag + tid * 32, (unsigned)(s + 1));
  }
}

// ---------------- DEC domain: wg 128..255 (master = 160) ----------------
template<bool MASTER>
__device__ void run_dec(const Params& p, int wg, int tid,
                        unsigned short* Abuf, float* pl, float* gates,
                        float* cst, float* sm, unsigned short* ahst, unsigned short* hst) {
  const int lane = tid & 63;
  const int v = tid >> 6;
  const int wgl = wg - 128;
  const int Tb = wgl * 2;

  bf16x8 bfa[10], bfb[10];
#pragma unroll
  for (int j = 0; j < 10; ++j) {
    const int c = v + 8 * j;
    const unsigned short* bp = p.wpd + ((size_t)(Tb * 80 + c) * 64 + lane) * 8;
    bfa[j] = *(const bf16x8*)bp;
    bfb[j] = *(const bf16x8*)(bp + (size_t)80 * 64 * 8);
  }
  const int melb = wgl >> 2, melc4 = wgl & 3;

  unsigned gen = 0;
  for (int i = 0; i < 500; ++i) {
    const int ib = i & 1;
    const unsigned short* ahb_i  = ib ? p.ahb1 : p.ahb0;     // ah_i
    const unsigned short* ctxb_i = ib ? p.ctxb1 : p.ctxb0;   // ctx_i
    const unsigned short* dhb_prev = ib ? p.dhb0 : p.dhb1;   // dh_{i-1}
    unsigned short*       dhb_cur  = ib ? p.dhb1 : p.dhb0;   // dh_i

    // wait for att to publish step i
    if (tid == 0) {
      while ((int)ld_coh32(p.attflag + (wg & 7) * 32) < i + 1)
        __builtin_amdgcn_s_sleep(4);
    }
    __syncthreads();

    // decLSTM_i
    gemm_tile2<80, 10, 5, false>(p, bfa, bfb, lane, v, i, ctxb_i, ahb_i, dhb_prev, Abuf, pl, tid);
    lstm_tail<false>(p, wgl, tid, (unsigned)i, dhb_cur, pl, gates, cst, hst);

    dbar<MASTER>(p, p.dbf, 128, wg, tid, ++gen);

    // mel_i / gate_i (reads dh_i, ctx_i)
    {
      if (tid < 384) {
        unsigned long long q;
        if (tid < 256) q = ld_coh64((const unsigned long long*)(dhb_cur + (size_t)melb * 1024) + tid);
        else           q = ld_coh64((const unsigned long long*)(ctxb_i + (size_t)melb * 512) + (tid - 256));
        *(unsigned long long*)&ahst[tid * 4] = q;
      }
      __syncthreads();
      int mi = tid >> 5, kg = tid & 31;
#pragma unroll
      for (int rep = 0; rep < 2; ++rep) {
        int mm = rep * 16 + mi;
        if (mm < 20) {
          int m = melc4 * 20 + mm;
          const float* pw = p.pjw + (size_t)m * 1536 + kg * 48;
          float acc = 0.f;
#pragma unroll 4
          for (int j = 0; j < 48; ++j) acc += bf2f(ahst[kg * 48 + j]) * pw[j];
          sm[mm * 32 + kg] = acc;
        }
      }
      if (melc4 == 3 && tid >= 384) {
        int kg2 = tid - 384;
        const float* gwp = p.gw + kg2 * 12;
        float acc = 0.f;
#pragma unroll
        for (int j = 0; j < 12; ++j) acc += bf2f(ahst[kg2 * 12 + j]) * gwp[j];
        sm[896 + kg2] = acc;
      }
      __syncthreads();
      if (tid < 20) {
        float r = p.pjb[melc4 * 20 + tid];
#pragma unroll
        for (int j = 0; j < 32; ++j) r += sm[tid * 32 + j];
        p.out[(size_t)melb * 40000 + (size_t)(melc4 * 20 + tid) * 500 + i] = r;
      }
      if (melc4 == 3 && tid == 384) {
        float r = p.gb[0];
#pragma unroll
        for (int j = 0; j < 128; ++j) r += sm[896 + j];
        p.out[(size_t)GOFF + (size_t)melb * 500 + i] = r;
      }
    }

    dbar<MASTER>(p, p.dbf, 128, wg, tid, ++gen);

    // publish: dec finished step i (mel done -> att may overwrite step-i buffers)
    if (MASTER && tid < 8) st_coh32(p.decflag + tid * 32, (unsigned)(i + 1));
  }
}

// ---------------- persistent scan kernel ----------------
__global__ void __launch_bounds__(512, 1) scan_kernel(Params p) {
  const int wg = blockIdx.x;
  const int tid = threadIdx.x;

  __shared__ __align__(16) unsigned short Abuf[32 * 1288];
  float* pl = (float*)Abuf;
  __shared__ float gates[32 * 33];
  __shared__ float cst[256];
  __shared__ float aw_l[292], awc_l[292];
  __shared__ float sm[1536];
  __shared__ unsigned short ahst[1536];
  __shared__ unsigned short cxst[512];
  __shared__ unsigned short hst[256];

  if (tid < 256) cst[tid] = 0.f;
  if (tid < 292) { aw_l[tid] = 0.f; awc_l[tid] = 0.f; }

  if (wg < 128) {
    if (wg == 32) run_att<true >(p, wg, tid, Abuf, pl, gates, cst, aw_l, awc_l, sm, ahst, cxst, hst);
    else          run_att<false>(p, wg, tid, Abuf, pl, gates, cst, aw_l, awc_l, sm, ahst, cxst, hst);
  } else {
    if (wg == 160) run_dec<true >(p, wg, tid, Abuf, pl, gates, cst, sm, ahst, hst);
    else           run_dec<false>(p, wg, tid, Abuf, pl, gates, cst, sm, ahst, hst);
  }
}

// ---------------- host ----------------
extern "C" void kernel_launch(void* const* d_in, const int* in_sizes, int n_in,
                              void* d_out, int out_size, void* d_ws, size_t ws_size,
                              hipStream_t stream) {
  Params p;
  p.memory = (const float*)d_in[0];
  p.dec_in = (const float*)d_in[1];
  p.mlen   = (const int*)d_in[2];
  p.pw1  = (const float*)d_in[3];
  p.pw2  = (const float*)d_in[4];
  p.awih = (const float*)d_in[5];
  p.awhh = (const float*)d_in[6];
  p.abih = (const float*)d_in[7];
  p.abhh = (const float*)d_in[8];
  p.qw   = (const float*)d_in[9];
  p.mw   = (const float*)d_in[10];
  p.vw   = (const float*)d_in[11];
  p.lcw  = (const float*)d_in[12];
  p.ldw  = (const float*)d_in[13];
  p.dwih = (const float*)d_in[14];
  p.dwhh = (const float*)d_in[15];
  p.dbih = (const float*)d_in[16];
  p.dbhh = (const float*)d_in[17];
  p.pjw  = (const float*)d_in[18];
  p.pjb  = (const float*)d_in[19];
  p.gw   = (const float*)d_in[20];
  p.gb   = (const float*)d_in[21];
  p.out  = (float*)d_out;

  char* cur = (char*)d_ws;
  auto allocf = [&](size_t n) { float* r = (float*)cur; cur += n * sizeof(float); return r; };
  auto allocs = [&](size_t n) { unsigned short* r = (unsigned short*)cur; cur += n * sizeof(unsigned short); return r; };
  // mutable state (memset each launch)
  p.ahb0 = allocs(32 * 1024); p.ahb1 = allocs(32 * 1024);
  p.dhb0 = allocs(32 * 1024); p.dhb1 = allocs(32 * 1024);
  p.ctxb0 = allocs(32 * 512); p.ctxb1 = allocs(32 * 512);
  p.slots   = (unsigned*)cur; cur += 256 * 32 * sizeof(unsigned);
  p.abf     = (unsigned*)cur; cur += 8 * 32 * sizeof(unsigned);
  p.dbf     = (unsigned*)cur; cur += 8 * 32 * sizeof(unsigned);
  p.attflag = (unsigned*)cur; cur += 8 * 32 * sizeof(unsigned);
  p.decflag = (unsigned*)cur; cur += 8 * 32 * sizeof(unsigned);
  size_t state_bytes = (size_t)(cur - (char*)d_ws);
  // static
  p.x1   = allocf((size_t)500 * 32 * 256);
  p.w1t  = allocf(80 * 256);
  p.w2t  = allocf(256 * 256);
  p.mwt  = allocf(512 * 128);
  p.ldwt = allocf(32 * 128);
  p.ba   = allocf(4096);
  p.bd   = allocf(4096);
  p.pre_bf  = allocs((size_t)500 * 32 * 256);
  p.pm_bf   = allocs((size_t)32 * 256 * 128);
  p.mem_t   = allocs((size_t)32 * 512 * 256);
  p.qw_bf   = allocs(128 * 1024);
  p.wpa     = allocs((size_t)256 * 56 * 64 * 8);
  p.wpd     = allocs((size_t)256 * 80 * 64 * 8);
  p.mma = (unsigned*)cur; cur += 512000u * 4;
  p.mmd = (unsigned*)cur; cur += 512000u * 4;
  p.mm1 = (unsigned*)cur; cur += 128256u * 4;
  p.mm2 = (unsigned*)cur; cur += 128256u * 4;

  (void)hipMemsetAsync(d_ws, 0, state_bytes, stream);

  unsigned k[8];
  {
    unsigned o0, o1;
    tf_block(0u, 1u, 0u, 0u, o0, o1); k[0] = o0; k[1] = o1;
    tf_block(0u, 1u, 0u, 1u, o0, o1); k[2] = o0; k[3] = o1;
    tf_block(0u, 1u, 0u, 2u, o0, o1); k[4] = o0; k[5] = o1;
    tf_block(0u, 1u, 0u, 3u, o0, o1); k[6] = o0; k[7] = o1;
  }

  maskgen_kernel<<<(1280512 + 255) / 256, 256, 0, stream>>>(p, k[0], k[1], k[2], k[3], k[4], k[5], k[6], k[7]);
  prep_misc<<<(4489216 + 255) / 256, 256, 0, stream>>>(p);
  pack_att<<<(917504 + 255) / 256, 256, 0, stream>>>(p);
  pack_dec<<<(1310720 + 255) / 256, 256, 0, stream>>>(p);
  prenet1_kernel<<<2000, 256, 0, stream>>>(p);
  prenet2_kernel<<<2000, 256, 0, stream>>>(p);
  pm_kernel<<<512, 128, 0, stream>>>(p);

  void* args[] = { (void*)&p };
  (void)hipLaunchCooperativeKernel((const void*)scan_kernel, dim3(256), dim3(512), args, 0, stream);
}